// Round 17
// baseline (75.323 us; speedup 1.0000x reference)
//
#include <hip/hip_runtime.h>
#include <hip/hip_bf16.h>

#define NB   32
#define CIN  128
#define COUT 256
#define HH   56
#define WW   56
#define CH   59        // padded B-row length in 16B chunks (944 B = 59*16)

typedef __attribute__((ext_vector_type(8))) short short8;   // 8 bf16 (4 VGPRs)
typedef __attribute__((ext_vector_type(4))) float f32x4;    // MFMA accumulator

// round-to-nearest-even fp32 -> bf16 (raw u16)
__device__ __forceinline__ unsigned short f2bf(float f) {
    unsigned int u = __builtin_bit_cast(unsigned int, f);
    u = u + 0x7fffu + ((u >> 16) & 1u);
    return (unsigned short)(u >> 16);
}

// ---------------------------------------------------------------------------
// Pre-pass: weights OIHW f32 -> wt2 in EXACT MFMA A-fragment order:
//   chunk ((s*16 + f)*64 + lane), elem j:  w[o=f*16+r][c=cc*32+g*8+j][tap t]
//   (s = K-step: t = s>>2, cc = s&3;  lane: g = lane>>4, r = lane&15)
// A wave's per-step fragment load is ONE coalesced global_load_dwordx4,
// L1/L2-resident (576 KB total, same stream for every block).
// ---------------------------------------------------------------------------
__global__ __launch_bounds__(256) void wpose_kernel(const float* __restrict__ w,
                                                    unsigned short* __restrict__ wt2) {
    int q = blockIdx.x * 256 + threadIdx.x;
    if (q >= 36 * 16 * 64 * 8) return;
    int j = q & 7;
    int l = (q >> 3) & 63;
    int f = (q >> 9) & 15;
    int s = q >> 13;
    int g = l >> 4, r = l & 15;
    int t = s >> 2, cc = s & 3;
    int o = f * 16 + r;
    int c = cc * 32 + g * 8 + j;
    wt2[q] = f2bf(w[((size_t)o * CIN + c) * 9 + t]);
}

// ---------------------------------------------------------------------------
// Main conv: block = 256 Cout x 224 spatial (4 output rows h0..h0+3),
// 512 threads = 8 waves as 4(M) x 2(N); wave = 64 Cout x 112 cols
// (4 M-frags x 7 N-frags of 16x16x32; Fm=4/Fn=7 = measured balanced point).
// 36 K-steps, barrier-free inside each kh-phase.
//
// r16 = the missing ablation cell: r5's PLAIN direct-global-A K-loop (the
// measured-best compute loop: 69 us, zero in-loop asm/ring/dbuf) + the fast
// float4 fused transpose (r12/r13) + two new trims:
//   * pad-only LDS zeroing (192 pad chunks + boundary rows, not all 90 KB)
//   * split transpose: rows 0..3 -> barrier -> rows 4..5 transpose code
//     issues BEFORE the kh=0 K-steps (latency hides under 12 steps that
//     only read rows 0..3) -> barrier -> kh=1,2 steps.
//   B layout: chunk ((row*16+gc)*59 + wpos), 8 ch; wpos 0/57 + OOB rows = 0.
//   All K-loop B addressing = 16-bit ds_read immediates.
// LDS = 90624 B.
// ---------------------------------------------------------------------------
__global__ __launch_bounds__(512) void conv_mfma_kernel(
        const float* __restrict__ x,
        const unsigned short* __restrict__ wt2,
        const float* __restrict__ bias,
        float* __restrict__ out) {
    __shared__ unsigned short ldsB[6 * 16 * CH * 8];    // 90624 B

    const int tid  = threadIdx.x;
    const int h0   = blockIdx.x * 4, n = blockIdx.y;
    const int wid  = tid >> 6, lane = tid & 63;
    const int wm   = wid >> 1, wn = wid & 1;            // 4M x 2N wave grid
    const int g    = lane >> 4, r = lane & 15;

    const uint4 z = {0u, 0u, 0u, 0u};

    // ---- phase 0: zero ONLY pad chunks (wpos 0,57 all rows) + OOB rows ----
    if (tid < 192) {                        // 6 rows x 16 gc x {0,57}
        int row = tid / 32, sub = tid & 31;
        int gc = sub >> 1, wp = (sub & 1) ? 57 : 0;
        *(uint4*)&ldsB[(size_t)((row * 16 + gc) * CH + wp) * 8] = z;
    }
    if (h0 == 0) {                          // input row h0-1 OOB -> row 0 = 0
        for (int i = tid; i < 16 * CH; i += 512)
            *(uint4*)&ldsB[(size_t)i * 8] = z;
    }
    if (h0 == 52) {                         // input row h0+4 OOB -> row 5 = 0
        for (int i = tid; i < 16 * CH; i += 512)
            *(uint4*)&ldsB[(size_t)(5 * 16 * CH + i) * 8] = z;
    }

    const float* xn = x + (size_t)n * CIN * HH * WW;

    // ---- transpose rows 0..3 (float4-vectorized, unit = (row, cp, w4)) ----
    for (int i = tid; i < 4 * 64 * 14; i += 512) {      // 3584 units
        int w4  = i % 14;
        int t1  = i / 14;
        int cp  = t1 & 63;                  // channel pair: c = 2cp, 2cp+1
        int row = t1 >> 6;                  // 0..3 -> input row h0+row-1
        int hs  = h0 + row - 1;
        if ((unsigned)hs < HH) {
            const float* p = xn + ((size_t)(2 * cp) * HH + hs) * WW + 4 * w4;
            float4 va = *(const float4*)p;
            float4 vb = *(const float4*)(p + HH * WW);
            int gc = cp >> 2, e = cp & 3;
            #pragma unroll
            for (int j = 0; j < 4; ++j) {
                int wpos = 4 * w4 + j + 1;
                unsigned int pk = (unsigned int)f2bf(((const float*)&va)[j])
                                | ((unsigned int)f2bf(((const float*)&vb)[j]) << 16);
                ((unsigned int*)ldsB)[((row * 16 + gc) * CH + wpos) * 4 + e] = pk;
            }
        }
    }
    __syncthreads();    // rows 0..3 + pads ready (kh=0 reads only rows 0..3)

    // ---- transpose rows 4..5: issues before kh=0 steps, completes before
    //      the second barrier (latency hidden under 12 K-steps) ----
    for (int i = tid; i < 2 * 64 * 14; i += 512) {      // 1792 units
        int w4  = i % 14;
        int t1  = i / 14;
        int cp  = t1 & 63;
        int row = 4 + (t1 >> 6);            // 4..5 -> input row h0+row-1
        int hs  = h0 + row - 1;
        if ((unsigned)hs < HH) {
            const float* p = xn + ((size_t)(2 * cp) * HH + hs) * WW + 4 * w4;
            float4 va = *(const float4*)p;
            float4 vb = *(const float4*)(p + HH * WW);
            int gc = cp >> 2, e = cp & 3;
            #pragma unroll
            for (int j = 0; j < 4; ++j) {
                int wpos = 4 * w4 + j + 1;
                unsigned int pk = (unsigned int)f2bf(((const float*)&va)[j])
                                | ((unsigned int)f2bf(((const float*)&vb)[j]) << 16);
                ((unsigned int*)ldsB)[((row * 16 + gc) * CH + wpos) * 4 + e] = pk;
            }
        }
    }

    // per-lane B base pointers for the 7 N-fragments
    const unsigned short* bbase[7];
    #pragma unroll
    for (int ni = 0; ni < 7; ++ni) {
        int c  = ni * 16 + r;
        int hr = (c >= 56) ? 1 : 0;
        int lo = hr * (16 * CH) + (c - hr * 56);
        bbase[ni] = &ldsB[(size_t)((wn * 32 + g) * CH + lo) * 8];
    }

    f32x4 acc[4][7];
    #pragma unroll
    for (int mi = 0; mi < 4; ++mi)
        #pragma unroll
        for (int ni = 0; ni < 7; ++ni)
            #pragma unroll
            for (int v = 0; v < 4; ++v) acc[mi][ni][v] = 0.f;

    // wave's A base: fragment f = wm*4 + mi, chunk ((s*16+f)*64 + lane)
    const short8* abase = (const short8*)wt2 + (size_t)(wm * 4) * 64 + lane;

    #define K_STEP(t_, cc_)                                                     \
        {                                                                       \
            const int s_ = (t_) * 4 + (cc_);                                    \
            const int kh_ = (t_) / 3, kw_ = (t_) - 3 * ((t_) / 3);              \
            const int boff_ = kh_ * 15104 + (cc_) * 3776 + kw_ * 16;            \
            short8 a_[4];                                                       \
            _Pragma("unroll")                                                   \
            for (int mi = 0; mi < 4; ++mi)                                      \
                a_[mi] = abase[(size_t)s_ * 1024 + mi * 64];                    \
            short8 b_[7];                                                       \
            _Pragma("unroll")                                                   \
            for (int ni = 0; ni < 7; ++ni)                                      \
                b_[ni] = *(const short8*)((const char*)bbase[ni] + boff_);      \
            _Pragma("unroll")                                                   \
            for (int mi = 0; mi < 4; ++mi)                                      \
                _Pragma("unroll")                                               \
                for (int ni = 0; ni < 7; ++ni)                                  \
                    acc[mi][ni] = __builtin_amdgcn_mfma_f32_16x16x32_bf16(      \
                        a_[mi], b_[ni], acc[mi][ni], 0, 0, 0);                  \
        }

    // ---- kh = 0 taps (t = 0..2): read LDS rows 0..3 only ----
    #pragma unroll
    for (int t = 0; t < 3; ++t)
        #pragma unroll
        for (int cc = 0; cc < 4; ++cc)
            K_STEP(t, cc)

    __syncthreads();    // rows 4..5 now visible

    // ---- kh = 1,2 taps (t = 3..8) ----
    #pragma unroll
    for (int t = 3; t < 9; ++t)
        #pragma unroll
        for (int cc = 0; cc < 4; ++cc)
            K_STEP(t, cc)

    // ---- epilogue: D col = r (spatial), row = g*4+v (Cout within frag) ----
    #pragma unroll
    for (int mi = 0; mi < 4; ++mi) {
        const int o0 = wm * 64 + mi * 16 + 4 * g;
        const float4 bv = *(const float4*)&bias[o0];
        #pragma unroll
        for (int ni = 0; ni < 7; ++ni) {
            const int c  = ni * 16 + r;
            const int hr = (c >= 56) ? 1 : 0;
            const int h  = h0 + wn * 2 + hr;
            const int w  = c - hr * 56;
            #pragma unroll
            for (int v = 0; v < 4; ++v) {
                out[((size_t)(n * COUT + o0 + v) * HH + h) * WW + w] =
                    acc[mi][ni][v] + ((const float*)&bv)[v];
            }
        }
    }
}

extern "C" void kernel_launch(void* const* d_in, const int* in_sizes, int n_in,
                              void* d_out, int out_size, void* d_ws, size_t ws_size,
                              hipStream_t stream) {
    const float* x  = (const float*)d_in[0];   // (32,128,56,56)
    const float* wk = (const float*)d_in[1];   // (256,128,3,3)
    const float* b  = (const float*)d_in[2];   // (256,)
    float* out = (float*)d_out;

    unsigned short* wt2 = (unsigned short*)d_ws;   // 294,912 elems = 590 KB

    wpose_kernel<<<(36 * 16 * 64 * 8 + 255) / 256, 256, 0, stream>>>(wk, wt2);
    dim3 gc(14, NB);                               // 4 output rows per block
    conv_mfma_kernel<<<gc, 512, 0, stream>>>(x, wt2, b, out);
    (void)ws_size; (void)in_sizes; (void)n_in; (void)out_size;
}